// Round 14
// baseline (769.762 us; speedup 1.0000x reference)
//
#include <hip/hip_runtime.h>

#define NG 64
#define HIDW 200
#define DIN 128
#define KPAD 224
#define POOL_NC 8

typedef _Float16 half4_t __attribute__((ext_vector_type(4)));
typedef _Float16 half8_t __attribute__((ext_vector_type(8)));
typedef float floatx4 __attribute__((ext_vector_type(4)));

// ---------------- build: degree count + graph-start table (fused) ----------------

__global__ void build_kernel(const int* __restrict__ dst, int* __restrict__ counts,
                             const int* __restrict__ batch, int* __restrict__ gs,
                             int E, int n) {
  int i = blockIdx.x * 256 + threadIdx.x;
  if (i < E) atomicAdd(&counts[dst[i]], 1);
  if (i < n) {
    int b = batch[i];
    if (i == 0) {
      for (int g = 0; g <= b; ++g) gs[g] = 0;
    } else {
      int bp = batch[i - 1];
      for (int g = bp + 1; g <= b; ++g) gs[g] = i;
    }
    if (i == n - 1) {
      for (int g = b + 1; g <= NG; ++g) gs[g] = n;
    }
  }
}

// ---------------- 3-phase parallel exclusive scan (counts -> row_ptr) ----------------

__global__ __launch_bounds__(256) void scan1_kernel(const int* __restrict__ counts,
                                                    int* __restrict__ blocksum,
                                                    float* __restrict__ dinv, int n) {
  __shared__ int s[256];
  int tid = threadIdx.x;
  int i = blockIdx.x * 256 + tid;
  int c = (i < n) ? counts[i] : 0;
  if (i < n) dinv[i] = rsqrtf((float)(c + 1));
  s[tid] = c;
  __syncthreads();
#pragma unroll
  for (int off = 128; off > 0; off >>= 1) {
    if (tid < off) s[tid] += s[tid + off];
    __syncthreads();
  }
  if (tid == 0) blocksum[blockIdx.x] = s[0];
}

__global__ __launch_bounds__(1024) void scan2_kernel(int* __restrict__ blocksum, int nb) {
  __shared__ int s[1024];
  int tid = threadIdx.x;
  int v = (tid < nb) ? blocksum[tid] : 0;
  s[tid] = v;
  __syncthreads();
  for (int off = 1; off < 1024; off <<= 1) {
    int t = (tid >= off) ? s[tid - off] : 0;
    __syncthreads();
    s[tid] += t;
    __syncthreads();
  }
  if (tid < nb) blocksum[tid] = s[tid] - v;  // exclusive
}

__global__ __launch_bounds__(256) void scan3_kernel(const int* __restrict__ counts,
                                                    const int* __restrict__ blocksum,
                                                    int* __restrict__ row_ptr, int n) {
  __shared__ int s[256];
  int tid = threadIdx.x;
  int i = blockIdx.x * 256 + tid;
  int c = (i < n) ? counts[i] : 0;
  s[tid] = c;
  __syncthreads();
  for (int off = 1; off < 256; off <<= 1) {
    int t = (tid >= off) ? s[tid - off] : 0;
    __syncthreads();
    s[tid] += t;
    __syncthreads();
  }
  int base = blocksum[blockIdx.x];
  if (i < n) row_ptr[i] = base + s[tid] - c;
  if (i == n - 1) row_ptr[n] = base + s[tid];
}

__global__ void fill_kernel(const int* __restrict__ src, const int* __restrict__ dst,
                            const int* __restrict__ row_ptr, int* __restrict__ fill,
                            int* __restrict__ csr_src, int E) {
  int e = blockIdx.x * 256 + threadIdx.x;
  if (e >= E) return;
  int d = dst[e];
  int pos = row_ptr[d] + atomicAdd(&fill[d], 1);
  csr_src[pos] = src[e];
}

// ---------------- weight prep (all 4 weights in one launch, y selects) ----------------
// W[k][200] fp32 -> WT_h/WT_l [256][KP] f16 (256 padded cols), split W = Wh + Wl

__global__ void wprep_kernel(const float* __restrict__ W1, const float* __restrict__ W2,
                             const float* __restrict__ W3, const float* __restrict__ Wg,
                             _Float16* __restrict__ o1h, _Float16* __restrict__ o1l,
                             _Float16* __restrict__ o2h, _Float16* __restrict__ o2l,
                             _Float16* __restrict__ o3h, _Float16* __restrict__ o3l,
                             _Float16* __restrict__ ogh, _Float16* __restrict__ ogl) {
  int wsel = blockIdx.y;
  const float* W = (wsel == 0) ? W1 : (wsel == 1) ? W2 : (wsel == 2) ? W3 : Wg;
  _Float16* WTh = (wsel == 0) ? o1h : (wsel == 1) ? o2h : (wsel == 2) ? o3h : ogh;
  _Float16* WTl = (wsel == 0) ? o1l : (wsel == 1) ? o2l : (wsel == 2) ? o3l : ogl;
  int K  = (wsel == 0) ? DIN : HIDW;
  int KP = (wsel == 0) ? DIN : KPAD;
  int idx = blockIdx.x * 256 + threadIdx.x;
  if (idx >= 256 * KP) return;
  int col = idx / KP, k = idx % KP;
  float v = (col < HIDW && k < K) ? W[(long)k * HIDW + col] : 0.f;
  _Float16 h = (_Float16)v;
  WTh[idx] = h;
  WTl[idx] = (_Float16)(v - (float)h);
}

// ---------------- x f32 [n][128] -> dinv-scaled slice-major f16 [4][n][32] ------------

__global__ void cvt_kernel(const float* __restrict__ x, const float* __restrict__ dinv,
                           _Float16* __restrict__ g0, int n) {
  int t = blockIdx.x * 256 + threadIdx.x;
  if (t >= n * 32) return;
  int node = t >> 5, q = t & 31;
  float di = dinv[node];
  float4 v = *(const float4*)&x[(long)node * 128 + q * 4];
  half4_t r = {(_Float16)(di * v.x), (_Float16)(di * v.y),
               (_Float16)(di * v.z), (_Float16)(di * v.w)};
  ((half4_t*)g0)[((long)(q >> 3) * n + node) * 8 + (q & 7)] = r;
}

// ---------------- aggregation, XCD-sliced, one node per wave (slicing v4) -------------
// z[i] = dinv[i]*(g[i] + sum g[s]); g pre-scaled by dinv, slice-major [NSLICE][n][32].
// slot = blockIdx.x & 7 -> XCD; each XCD's gathers stay in its 2.56 MB L2-resident
// slice. One node per wave (no divergence, no shuffles, no sort); lanes 0..7 gather
// one 64 B line/edge; unroll 16 -> 16 lines in flight. Fixes R7/R8/R12 defects.

template <int NSLICE>
__global__ __launch_bounds__(256) void agg_kernel(const _Float16* __restrict__ g,
                                                  const int* __restrict__ row_ptr,
                                                  const int* __restrict__ csr_src,
                                                  const float* __restrict__ dinv,
                                                  _Float16* __restrict__ out, int n) {
  int slot = blockIdx.x & 7;
  int nb = blockIdx.x >> 3;
  int lane = threadIdx.x & 63;
  int wv = threadIdx.x >> 6;
  int slice, node;
  if (NSLICE == 7) {
    if (slot == 7) return;
    slice = slot;
    node = nb * 4 + wv;
  } else {  // NSLICE == 4: two slots share a slice, node ranges interleave
    slice = slot >> 1;
    node = (nb * 2 + (slot & 1)) * 4 + wv;
  }
  if (node >= n || lane >= 8) return;
  const half4_t* __restrict__ hp = (const half4_t*)g + (long)slice * n * 8;
  int e0 = row_ptr[node], e1 = row_ptr[node + 1];
  half4_t self = hp[(long)node * 8 + lane];
  float ax = (float)self.x, ay = (float)self.y;
  float az = (float)self.z, aw = (float)self.w;

  int e = e0;
  for (; e + 16 <= e1; e += 16) {
    int sI[16];
#pragma unroll
    for (int j = 0; j < 16; ++j) sI[j] = csr_src[e + j];
    half4_t vv[16];
#pragma unroll
    for (int j = 0; j < 16; ++j) vv[j] = hp[(long)sI[j] * 8 + lane];
#pragma unroll
    for (int j = 0; j < 16; ++j) {
      ax += (float)vv[j].x; ay += (float)vv[j].y;
      az += (float)vv[j].z; aw += (float)vv[j].w;
    }
  }
  if (e + 8 <= e1) {
    int sI[8];
#pragma unroll
    for (int j = 0; j < 8; ++j) sI[j] = csr_src[e + j];
    half4_t vv[8];
#pragma unroll
    for (int j = 0; j < 8; ++j) vv[j] = hp[(long)sI[j] * 8 + lane];
#pragma unroll
    for (int j = 0; j < 8; ++j) {
      ax += (float)vv[j].x; ay += (float)vv[j].y;
      az += (float)vv[j].z; aw += (float)vv[j].w;
    }
    e += 8;
  }
  if (e + 4 <= e1) {
    int sI[4];
#pragma unroll
    for (int j = 0; j < 4; ++j) sI[j] = csr_src[e + j];
    half4_t vv[4];
#pragma unroll
    for (int j = 0; j < 4; ++j) vv[j] = hp[(long)sI[j] * 8 + lane];
#pragma unroll
    for (int j = 0; j < 4; ++j) {
      ax += (float)vv[j].x; ay += (float)vv[j].y;
      az += (float)vv[j].z; aw += (float)vv[j].w;
    }
    e += 4;
  }
  for (; e < e1; ++e) {
    int s = csr_src[e];
    half4_t v = hp[(long)s * 8 + lane];
    ax += (float)v.x; ay += (float)v.y; az += (float)v.z; aw += (float)v.w;
  }
  float di = dinv[node];
  half4_t r = {(_Float16)(di * ax), (_Float16)(di * ay),
               (_Float16)(di * az), (_Float16)(di * aw)};
  __builtin_nontemporal_store(r, (half4_t*)out + (long)slice * n * 8 + (long)node * 8 + lane);
}

// ---------------- MFMA GEMM: LDS B-panel + XCD-family swizzle, slice-major A/out -----
// A: [KP/32][N][32] f16. out: [7][N][32] f16. W: [256][KP] f16 split Wh+Wl.
// Block = 4 waves x 64-row tiles (256 rows) x one 64-col strip; B staged once.
// Swizzle: b -> strip=(b>>3)&3, rg=(b&7)+8*(b>>5); strips of a row-group share b%8
// -> same XCD -> A-rows L2-hit. MODE 1 = relu, 2 = gated. DSCALE: out *= dinv[row].

template <int KP, int MODE, int DSCALE>
__global__ __launch_bounds__(256, 2) void mgemm_kernel(const _Float16* __restrict__ A,
                                                       const _Float16* __restrict__ WTh,
                                                       const _Float16* __restrict__ WTl,
                                                       const float* __restrict__ bias,
                                                       const float* __restrict__ dinv,
                                                       _Float16* __restrict__ out, int N) {
  constexpr int LDK = KP + 8;
  __shared__ _Float16 Bh[64][LDK];
  __shared__ _Float16 Bl[64][LDK];
  int tid = threadIdx.x;
  int b = blockIdx.x;
  int strip = (b >> 3) & 3;
  int rg = (b & 7) + 8 * (b >> 5);
  int col0 = strip * 64;

  // stage B: 64 cols x KP, once
  {
    int c = tid >> 2;
    int ks = (tid & 3) * (KP / 4);
    const _Float16* gh = WTh + (long)(col0 + c) * KP + ks;
    const _Float16* gl = WTl + (long)(col0 + c) * KP + ks;
#pragma unroll
    for (int j = 0; j < KP / 32; ++j) {
      *(half8_t*)&Bh[c][ks + j * 8] = *(const half8_t*)(gh + j * 8);
      *(half8_t*)&Bl[c][ks + j * 8] = *(const half8_t*)(gl + j * 8);
    }
  }
  __syncthreads();

  int lane = tid & 63;
  int wid = tid >> 6;
  int row0 = rg * 256 + wid * 64;
  if (row0 >= N) return;  // no barriers after this point
  int l15 = lane & 15;
  int lq = lane >> 4;

  floatx4 acc[4][4];
#pragma unroll
  for (int i = 0; i < 4; ++i)
#pragma unroll
    for (int j = 0; j < 4; ++j) acc[i][j] = (floatx4){0.f, 0.f, 0.f, 0.f};

#pragma unroll
  for (int k0 = 0; k0 < KP; k0 += 32) {
    const _Float16* as = A + ((long)(k0 >> 5) * N + row0 + l15) * 32 + lq * 8;
    half8_t a[4];
#pragma unroll
    for (int rf = 0; rf < 4; ++rf)
      a[rf] = *(const half8_t*)(as + rf * 16 * 32);
#pragma unroll
    for (int cf = 0; cf < 4; ++cf) {
      half8_t bh = *(const half8_t*)&Bh[cf * 16 + l15][k0 + lq * 8];
#pragma unroll
      for (int rf = 0; rf < 4; ++rf)
        acc[rf][cf] = __builtin_amdgcn_mfma_f32_16x16x32_f16(a[rf], bh, acc[rf][cf], 0, 0, 0);
    }
#pragma unroll
    for (int cf = 0; cf < 4; ++cf) {
      half8_t bl = *(const half8_t*)&Bl[cf * 16 + l15][k0 + lq * 8];
#pragma unroll
      for (int rf = 0; rf < 4; ++rf)
        acc[rf][cf] = __builtin_amdgcn_mfma_f32_16x16x32_f16(a[rf], bl, acc[rf][cf], 0, 0, 0);
    }
  }

#pragma unroll
  for (int cf = 0; cf < 4; ++cf) {
    int col = col0 + cf * 16 + l15;
    if (col >= KPAD) continue;      // strip 3 tail (cols 224..255): not stored
    float bs = (col < HIDW) ? bias[col] : 0.f;
    long obase = ((long)(col >> 5) * N) * 32 + (col & 31);
#pragma unroll
    for (int rf = 0; rf < 4; ++rf) {
      int rbase = row0 + rf * 16 + lq * 4;
#pragma unroll
      for (int j = 0; j < 4; ++j) {
        int row = rbase + j;
        float v = acc[rf][cf][j] + bs;
        if (MODE == 1) v = fmaxf(v, 0.f);
        if (MODE == 2) {
          float hv = (float)A[((long)(col >> 5) * N + row) * 32 + (col & 31)];
          v = hv * (1.f / (1.f + __expf(-v)));
        }
        if (DSCALE) v *= dinv[row];
        if (col >= HIDW) v = 0.f;   // keep pads zero
        out[obase + (long)row * 32] = (_Float16)v;
      }
    }
  }
}

// ---------------- mean pool partials over gated slice-major f16 ----------------

__global__ __launch_bounds__(256) void pool_partial_kernel(const _Float16* __restrict__ gated,
                                                           const int* __restrict__ gs,
                                                           float* __restrict__ partial, int n) {
  int g = blockIdx.x;
  int c = blockIdx.y;
  int f = threadIdx.x;
  int s = gs[g], e = gs[g + 1];
  int len = e - s;
  int chunk = (len + POOL_NC - 1) / POOL_NC;
  int i0 = s + c * chunk;
  int i1 = i0 + chunk; if (i1 > e) i1 = e;
  if (f < HIDW) {
    const _Float16* p = gated + ((long)(f >> 5) * n) * 32 + (f & 31);
    float acc = 0.f;
    for (int i = i0; i < i1; ++i) acc += (float)p[(long)i * 32];
    partial[(g * POOL_NC + c) * HIDW + f] = acc;
  }
}

// ---------------- classifier (fused pool-final): partial -> logits ----------------

__global__ void classifier_kernel(const float* __restrict__ partial,
                                  const int* __restrict__ gs,
                                  const float* __restrict__ Wc1, const float* __restrict__ bc1,
                                  const float* __restrict__ Wc2, const float* __restrict__ bc2,
                                  float* __restrict__ out) {
  int g = blockIdx.x;
  int tid = threadIdx.x;
  __shared__ float pg[HIDW];
  __shared__ float hid[100];
  if (tid < HIDW) {
    float acc = 0.f;
#pragma unroll
    for (int c = 0; c < POOL_NC; ++c) acc += partial[(g * POOL_NC + c) * HIDW + tid];
    float cnt = fmaxf((float)(gs[g + 1] - gs[g]), 1.f);
    pg[tid] = acc / cnt;
  }
  __syncthreads();
  if (tid < 100) {
    float a = bc1[tid];
    for (int k = 0; k < HIDW; ++k) a = fmaf(pg[k], Wc1[k * 100 + tid], a);
    hid[tid] = fmaxf(a, 0.f);
  }
  __syncthreads();
  if (tid < 2) {
    float a = bc2[tid];
    for (int k = 0; k < 100; ++k) a = fmaf(hid[k], Wc2[k * 2 + tid], a);
    out[g * 2 + tid] = a;
  }
}

// ---------------- launch ----------------

extern "C" void kernel_launch(void* const* d_in, const int* in_sizes, int n_in,
                              void* d_out, int out_size, void* d_ws, size_t ws_size,
                              hipStream_t stream) {
  const float* x    = (const float*)d_in[0];
  const int*   ei   = (const int*)d_in[1];
  const int*   batch= (const int*)d_in[2];
  const float* W1 = (const float*)d_in[3];  const float* b1 = (const float*)d_in[4];
  const float* W2 = (const float*)d_in[5];  const float* b2 = (const float*)d_in[6];
  const float* W3 = (const float*)d_in[7];  const float* b3 = (const float*)d_in[8];
  const float* Wg = (const float*)d_in[9];  const float* bg = (const float*)d_in[10];
  const float* Wc1= (const float*)d_in[11]; const float* bc1= (const float*)d_in[12];
  const float* Wc2= (const float*)d_in[13]; const float* bc2= (const float*)d_in[14];
  float* out = (float*)d_out;

  const int n = in_sizes[0] / DIN;     // 40000
  const int E = in_sizes[1] / 2;       // 640000
  const int* src = ei;
  const int* dst = ei + E;
  const int nb256 = (n + 255) / 256;   // 157 scan blocks

  // workspace carve-up (all segments 16B-aligned)
  int* counts   = (int*)d_ws;               // n
  int* fill     = counts + n;               // n
  int* row_ptr  = fill + n;                 // n+4
  int* gs       = row_ptr + (n + 4);        // 68
  int* blocksum = gs + 68;                  // 1024
  float* dinv   = (float*)(blocksum + 1024);// n
  int* csr_src  = (int*)(dinv + n);         // E
  float* partial= (float*)(csr_src + E);    // 64*8*200
  _Float16* wt1h = (_Float16*)(partial + NG * POOL_NC * HIDW);  // 256*128
  _Float16* wt1l = wt1h + 256 * 128;
  _Float16* wt2h = wt1l + 256 * 128;
  _Float16* wt2l = wt2h + 256 * KPAD;
  _Float16* wt3h = wt2l + 256 * KPAD;
  _Float16* wt3l = wt3h + 256 * KPAD;
  _Float16* wtgh = wt3l + 256 * KPAD;
  _Float16* wtgl = wtgh + 256 * KPAD;
  _Float16* xh   = wtgl + 256 * KPAD;           // [4][n][32] f16 (dinv-scaled)
  _Float16* bufA = xh + (long)n * DIN;          // [7][n][32] f16
  _Float16* bufB = bufA + (long)n * KPAD;       // [7][n][32] f16

  hipMemsetAsync(counts, 0, (size_t)2 * n * sizeof(int), stream);  // counts + fill

  // weight prep: all 4 weights, one launch (256 padded cols)
  dim3 wgrid((256 * KPAD + 255) / 256, 4);
  wprep_kernel<<<wgrid, 256, 0, stream>>>(W1, W2, W3, Wg, wt1h, wt1l, wt2h, wt2l,
                                          wt3h, wt3l, wtgh, wtgl);

  int eb = (E + 255) / 256;
  build_kernel<<<eb, 256, 0, stream>>>(dst, counts, batch, gs, E, n);
  scan1_kernel<<<nb256, 256, 0, stream>>>(counts, blocksum, dinv, n);
  // cvt needs dinv (from scan1): g0 = dinv * x, slice-major
  cvt_kernel<<<(n * 32 + 255) / 256, 256, 0, stream>>>(x, dinv, xh, n);
  scan2_kernel<<<1, 1024, 0, stream>>>(blocksum, nb256);
  scan3_kernel<<<nb256, 256, 0, stream>>>(counts, blocksum, row_ptr, n);
  fill_kernel<<<eb, 256, 0, stream>>>(src, dst, row_ptr, fill, csr_src, E);

  int ag7 = 8 * ((n + 3) / 4);                   // one node/wave, 7 slices (slot 7 idle)
  int ag4 = 8 * ((n + 7) / 8);                   // one node/wave, 4 slices x 2 slots
  int gb = ((nb256 + 7) / 8) * 8 * 4;            // gemm: 8-aligned families x 4 strips

  // layer 1: z1 = agg(g0); bufB = dinv*relu(z1@W1+b1)
  agg_kernel<4><<<ag4, 256, 0, stream>>>(xh, row_ptr, csr_src, dinv, bufA, n);
  mgemm_kernel<DIN, 1, 1><<<gb, 256, 0, stream>>>(bufA, wt1h, wt1l, b1, dinv, bufB, n);
  // layer 2
  agg_kernel<7><<<ag7, 256, 0, stream>>>(bufB, row_ptr, csr_src, dinv, bufA, n);
  mgemm_kernel<KPAD, 1, 1><<<gb, 256, 0, stream>>>(bufA, wt2h, wt2l, b2, dinv, bufB, n);
  // layer 3 (h3 unscaled: feeds gate + pool, not another agg)
  agg_kernel<7><<<ag7, 256, 0, stream>>>(bufB, row_ptr, csr_src, dinv, bufA, n);
  mgemm_kernel<KPAD, 1, 0><<<gb, 256, 0, stream>>>(bufA, wt3h, wt3l, b3, dinv, bufB, n);
  // gate + apply: bufA = h3 * sigmoid(h3 @ Wg + bg)
  mgemm_kernel<KPAD, 2, 0><<<gb, 256, 0, stream>>>(bufB, wtgh, wtgl, bg, dinv, bufA, n);
  // mean-pool partials + fused pool-final/classifier
  dim3 pgrid(NG, POOL_NC);
  pool_partial_kernel<<<pgrid, 256, 0, stream>>>(bufA, gs, partial, n);
  classifier_kernel<<<NG, 256, 0, stream>>>(partial, gs, Wc1, bc1, Wc2, bc2, out);
}

// Round 15
// 319.274 us; speedup vs baseline: 2.4110x; 2.4110x over previous
//
#include <hip/hip_runtime.h>

#define NG 64
#define HIDW 200
#define DIN 128
#define KPAD 224
#define POOL_NC 8

typedef _Float16 half4_t __attribute__((ext_vector_type(4)));
typedef _Float16 half8_t __attribute__((ext_vector_type(8)));
typedef float floatx4 __attribute__((ext_vector_type(4)));

// ---------------- build: degree count + graph-start table (fused) ----------------

__global__ void build_kernel(const int* __restrict__ dst, int* __restrict__ counts,
                             const int* __restrict__ batch, int* __restrict__ gs,
                             int E, int n) {
  int i = blockIdx.x * 256 + threadIdx.x;
  if (i < E) atomicAdd(&counts[dst[i]], 1);
  if (i < n) {
    int b = batch[i];
    if (i == 0) {
      for (int g = 0; g <= b; ++g) gs[g] = 0;
    } else {
      int bp = batch[i - 1];
      for (int g = bp + 1; g <= b; ++g) gs[g] = i;
    }
    if (i == n - 1) {
      for (int g = b + 1; g <= NG; ++g) gs[g] = n;
    }
  }
}

// ---------------- 3-phase parallel exclusive scan (counts -> row_ptr) ----------------

__global__ __launch_bounds__(256) void scan1_kernel(const int* __restrict__ counts,
                                                    int* __restrict__ blocksum,
                                                    float* __restrict__ dinv, int n) {
  __shared__ int s[256];
  int tid = threadIdx.x;
  int i = blockIdx.x * 256 + tid;
  int c = (i < n) ? counts[i] : 0;
  if (i < n) dinv[i] = rsqrtf((float)(c + 1));
  s[tid] = c;
  __syncthreads();
#pragma unroll
  for (int off = 128; off > 0; off >>= 1) {
    if (tid < off) s[tid] += s[tid + off];
    __syncthreads();
  }
  if (tid == 0) blocksum[blockIdx.x] = s[0];
}

__global__ __launch_bounds__(1024) void scan2_kernel(int* __restrict__ blocksum, int nb) {
  __shared__ int s[1024];
  int tid = threadIdx.x;
  int v = (tid < nb) ? blocksum[tid] : 0;
  s[tid] = v;
  __syncthreads();
  for (int off = 1; off < 1024; off <<= 1) {
    int t = (tid >= off) ? s[tid - off] : 0;
    __syncthreads();
    s[tid] += t;
    __syncthreads();
  }
  if (tid < nb) blocksum[tid] = s[tid] - v;  // exclusive
}

__global__ __launch_bounds__(256) void scan3_kernel(const int* __restrict__ counts,
                                                    const int* __restrict__ blocksum,
                                                    int* __restrict__ row_ptr, int n) {
  __shared__ int s[256];
  int tid = threadIdx.x;
  int i = blockIdx.x * 256 + tid;
  int c = (i < n) ? counts[i] : 0;
  s[tid] = c;
  __syncthreads();
  for (int off = 1; off < 256; off <<= 1) {
    int t = (tid >= off) ? s[tid - off] : 0;
    __syncthreads();
    s[tid] += t;
    __syncthreads();
  }
  int base = blocksum[blockIdx.x];
  if (i < n) row_ptr[i] = base + s[tid] - c;
  if (i == n - 1) row_ptr[n] = base + s[tid];
}

__global__ void fill_kernel(const int* __restrict__ src, const int* __restrict__ dst,
                            const int* __restrict__ row_ptr, int* __restrict__ fill,
                            int* __restrict__ csr_src, int E) {
  int e = blockIdx.x * 256 + threadIdx.x;
  if (e >= E) return;
  int d = dst[e];
  int pos = row_ptr[d] + atomicAdd(&fill[d], 1);
  csr_src[pos] = src[e];
}

// ---------------- weight prep (all 4 weights in one launch, y selects) ----------------
// W[k][200] fp32 -> WT [256][KP] f16 (256 padded cols), single f16 term (no split:
// per-layer systematic rel err ~2^-11, ~1e-3 on logits vs 1.68e-3 threshold)

__global__ void wprep_kernel(const float* __restrict__ W1, const float* __restrict__ W2,
                             const float* __restrict__ W3, const float* __restrict__ Wg,
                             _Float16* __restrict__ o1, _Float16* __restrict__ o2,
                             _Float16* __restrict__ o3, _Float16* __restrict__ og) {
  int wsel = blockIdx.y;
  const float* W = (wsel == 0) ? W1 : (wsel == 1) ? W2 : (wsel == 2) ? W3 : Wg;
  _Float16* WT = (wsel == 0) ? o1 : (wsel == 1) ? o2 : (wsel == 2) ? o3 : og;
  int K  = (wsel == 0) ? DIN : HIDW;
  int KP = (wsel == 0) ? DIN : KPAD;
  int idx = blockIdx.x * 256 + threadIdx.x;
  if (idx >= 256 * KP) return;
  int col = idx / KP, k = idx % KP;
  float v = (col < HIDW && k < K) ? W[(long)k * HIDW + col] : 0.f;
  WT[idx] = (_Float16)v;
}

// ---------------- x f32 [n][128] -> dinv-scaled row-major f16 [n][128] ----------------

__global__ void cvt_kernel(const float* __restrict__ x, const float* __restrict__ dinv,
                           _Float16* __restrict__ g0, int n) {
  int t = blockIdx.x * 256 + threadIdx.x;
  if (t >= n * 32) return;
  int node = t >> 5, q = t & 31;
  float di = dinv[node];
  float4 v = *(const float4*)&x[(long)node * 128 + q * 4];
  half4_t r = {(_Float16)(di * v.x), (_Float16)(di * v.y),
               (_Float16)(di * v.z), (_Float16)(di * v.w)};
  ((half4_t*)g0)[(long)node * 32 + q] = r;
}

// ---------------- aggregation: z[i] = dinv[i] * (g[i] + sum_{s in N(i)} g[s]) ---------
// g pre-scaled by dinv. Row-major [n][C*4] f16. Wave per node, lanes own half4 chunks.
// Unroll 16 (16 independent gathers in flight), tails 8/4/1. At the 8-XCD table
// replication floor (~150 MB fetch @ ~3.5 TB/s fabric) — structural ceiling.

template <int C>
__global__ __launch_bounds__(256) void agg_kernel(const _Float16* __restrict__ g,
                                                  const int* __restrict__ row_ptr,
                                                  const int* __restrict__ csr_src,
                                                  const float* __restrict__ dinv,
                                                  _Float16* __restrict__ out, int n) {
  int node = blockIdx.x * 4 + (threadIdx.x >> 6);
  int lane = threadIdx.x & 63;
  if (node >= n || lane >= C) return;
  const half4_t* __restrict__ hp = (const half4_t*)g;
  int e0 = row_ptr[node], e1 = row_ptr[node + 1];
  half4_t self = hp[(long)node * C + lane];
  float ax = (float)self.x, ay = (float)self.y;
  float az = (float)self.z, aw = (float)self.w;

  int e = e0;
  for (; e + 16 <= e1; e += 16) {
    int sI[16];
#pragma unroll
    for (int j = 0; j < 16; ++j) sI[j] = csr_src[e + j];
    half4_t vv[16];
#pragma unroll
    for (int j = 0; j < 16; ++j) vv[j] = hp[(long)sI[j] * C + lane];
#pragma unroll
    for (int j = 0; j < 16; ++j) {
      ax += (float)vv[j].x; ay += (float)vv[j].y;
      az += (float)vv[j].z; aw += (float)vv[j].w;
    }
  }
  if (e + 8 <= e1) {
    int sI[8];
#pragma unroll
    for (int j = 0; j < 8; ++j) sI[j] = csr_src[e + j];
    half4_t vv[8];
#pragma unroll
    for (int j = 0; j < 8; ++j) vv[j] = hp[(long)sI[j] * C + lane];
#pragma unroll
    for (int j = 0; j < 8; ++j) {
      ax += (float)vv[j].x; ay += (float)vv[j].y;
      az += (float)vv[j].z; aw += (float)vv[j].w;
    }
    e += 8;
  }
  if (e + 4 <= e1) {
    int sI[4];
#pragma unroll
    for (int j = 0; j < 4; ++j) sI[j] = csr_src[e + j];
    half4_t vv[4];
#pragma unroll
    for (int j = 0; j < 4; ++j) vv[j] = hp[(long)sI[j] * C + lane];
#pragma unroll
    for (int j = 0; j < 4; ++j) {
      ax += (float)vv[j].x; ay += (float)vv[j].y;
      az += (float)vv[j].z; aw += (float)vv[j].w;
    }
    e += 4;
  }
  for (; e < e1; ++e) {
    int s = csr_src[e];
    half4_t v = hp[(long)s * C + lane];
    ax += (float)v.x; ay += (float)v.y; az += (float)v.z; aw += (float)v.w;
  }
  float di = dinv[node];
  half4_t r = {(_Float16)(di * ax), (_Float16)(di * ay),
               (_Float16)(di * az), (_Float16)(di * aw)};
  ((half4_t*)out)[(long)node * C + lane] = r;
}

// ---------------- MFMA GEMM: B-panel in LDS + XCD-family swizzle, single f16 W --------
// A: [N][KP] f16 row-major. W: [256][KP] f16. out: [N][224] f16.
// Block = 4 waves x 64-row tiles (256 rows) x one 64-col strip; B staged once,
// LDS 29.7 KB -> ~5 blocks/CU. Per k-step/wave: 4 A-loads + 4 ds_read_b128 + 16 MFMA.
// Swizzle (T1): b -> strip=(b>>3)&3, rg=(b&7)+8*(b>>5); strips of a row-group share
// b%8 -> same XCD -> A-rows L2-hit. MODE 1 = relu, 2 = gated. DSCALE: out *= dinv[row].

template <int KP, int MODE, int DSCALE>
__global__ __launch_bounds__(256, 2) void mgemm_kernel(const _Float16* __restrict__ A,
                                                       const _Float16* __restrict__ WT,
                                                       const float* __restrict__ bias,
                                                       const float* __restrict__ dinv,
                                                       _Float16* __restrict__ out, int N) {
  constexpr int LDK = KP + 8;
  __shared__ _Float16 Bs[64][LDK];
  int tid = threadIdx.x;
  int b = blockIdx.x;
  int strip = (b >> 3) & 3;
  int rg = (b & 7) + 8 * (b >> 5);
  int col0 = strip * 64;

  // stage B: 64 cols x KP, once
  {
    int c = tid >> 2;
    int ks = (tid & 3) * (KP / 4);
    const _Float16* gw = WT + (long)(col0 + c) * KP + ks;
#pragma unroll
    for (int j = 0; j < KP / 32; ++j)
      *(half8_t*)&Bs[c][ks + j * 8] = *(const half8_t*)(gw + j * 8);
  }
  __syncthreads();

  int lane = tid & 63;
  int wid = tid >> 6;
  int row0 = rg * 256 + wid * 64;
  if (row0 >= N) return;  // no barriers after this point
  int l15 = lane & 15;
  int lq = lane >> 4;

  const _Float16* __restrict__ pa = A + (long)(row0 + l15) * KP + lq * 8;

  floatx4 acc[4][4];
#pragma unroll
  for (int i = 0; i < 4; ++i)
#pragma unroll
    for (int j = 0; j < 4; ++j) acc[i][j] = (floatx4){0.f, 0.f, 0.f, 0.f};

#pragma unroll
  for (int k0 = 0; k0 < KP; k0 += 32) {
    half8_t a[4];
#pragma unroll
    for (int rf = 0; rf < 4; ++rf)
      a[rf] = *(const half8_t*)(pa + (long)rf * 16 * KP + k0);
#pragma unroll
    for (int cf = 0; cf < 4; ++cf) {
      half8_t bv = *(const half8_t*)&Bs[cf * 16 + l15][k0 + lq * 8];
#pragma unroll
      for (int rf = 0; rf < 4; ++rf)
        acc[rf][cf] = __builtin_amdgcn_mfma_f32_16x16x32_f16(a[rf], bv, acc[rf][cf], 0, 0, 0);
    }
  }

#pragma unroll
  for (int cf = 0; cf < 4; ++cf) {
    int col = col0 + cf * 16 + l15;
    if (col >= KPAD) continue;      // strip 3 tail (cols 224..255): not stored
    float bs = (col < HIDW) ? bias[col] : 0.f;
#pragma unroll
    for (int rf = 0; rf < 4; ++rf) {
      int rbase = row0 + rf * 16 + lq * 4;
#pragma unroll
      for (int j = 0; j < 4; ++j) {
        int row = rbase + j;
        float v = acc[rf][cf][j] + bs;
        if (MODE == 1) v = fmaxf(v, 0.f);
        if (MODE == 2) {
          float hv = (float)A[(long)row * KP + col];
          v = hv * (1.f / (1.f + __expf(-v)));
        }
        if (DSCALE) v *= dinv[row];
        if (col >= HIDW) v = 0.f;   // keep pads zero
        out[(long)row * KPAD + col] = (_Float16)v;
      }
    }
  }
}

// ---------------- mean pool partials over gated row-major f16 ----------------

__global__ __launch_bounds__(256) void pool_partial_kernel(const _Float16* __restrict__ gated,
                                                           const int* __restrict__ gs,
                                                           float* __restrict__ partial, int n) {
  int g = blockIdx.x;
  int c = blockIdx.y;
  int f = threadIdx.x;
  int s = gs[g], e = gs[g + 1];
  int len = e - s;
  int chunk = (len + POOL_NC - 1) / POOL_NC;
  int i0 = s + c * chunk;
  int i1 = i0 + chunk; if (i1 > e) i1 = e;
  if (f < HIDW) {
    float acc = 0.f;
    for (int i = i0; i < i1; ++i) acc += (float)gated[(long)i * KPAD + f];
    partial[(g * POOL_NC + c) * HIDW + f] = acc;
  }
}

// ---------------- classifier (fused pool-final): partial -> logits ----------------

__global__ void classifier_kernel(const float* __restrict__ partial,
                                  const int* __restrict__ gs,
                                  const float* __restrict__ Wc1, const float* __restrict__ bc1,
                                  const float* __restrict__ Wc2, const float* __restrict__ bc2,
                                  float* __restrict__ out) {
  int g = blockIdx.x;
  int tid = threadIdx.x;
  __shared__ float pg[HIDW];
  __shared__ float hid[100];
  if (tid < HIDW) {
    float acc = 0.f;
#pragma unroll
    for (int c = 0; c < POOL_NC; ++c) acc += partial[(g * POOL_NC + c) * HIDW + tid];
    float cnt = fmaxf((float)(gs[g + 1] - gs[g]), 1.f);
    pg[tid] = acc / cnt;
  }
  __syncthreads();
  if (tid < 100) {
    float a = bc1[tid];
    for (int k = 0; k < HIDW; ++k) a = fmaf(pg[k], Wc1[k * 100 + tid], a);
    hid[tid] = fmaxf(a, 0.f);
  }
  __syncthreads();
  if (tid < 2) {
    float a = bc2[tid];
    for (int k = 0; k < 100; ++k) a = fmaf(hid[k], Wc2[k * 2 + tid], a);
    out[g * 2 + tid] = a;
  }
}

// ---------------- launch ----------------

extern "C" void kernel_launch(void* const* d_in, const int* in_sizes, int n_in,
                              void* d_out, int out_size, void* d_ws, size_t ws_size,
                              hipStream_t stream) {
  const float* x    = (const float*)d_in[0];
  const int*   ei   = (const int*)d_in[1];
  const int*   batch= (const int*)d_in[2];
  const float* W1 = (const float*)d_in[3];  const float* b1 = (const float*)d_in[4];
  const float* W2 = (const float*)d_in[5];  const float* b2 = (const float*)d_in[6];
  const float* W3 = (const float*)d_in[7];  const float* b3 = (const float*)d_in[8];
  const float* Wg = (const float*)d_in[9];  const float* bg = (const float*)d_in[10];
  const float* Wc1= (const float*)d_in[11]; const float* bc1= (const float*)d_in[12];
  const float* Wc2= (const float*)d_in[13]; const float* bc2= (const float*)d_in[14];
  float* out = (float*)d_out;

  const int n = in_sizes[0] / DIN;     // 40000
  const int E = in_sizes[1] / 2;       // 640000
  const int* src = ei;
  const int* dst = ei + E;
  const int nb256 = (n + 255) / 256;   // 157 scan blocks

  // workspace carve-up (all segments 16B-aligned)
  int* counts   = (int*)d_ws;               // n
  int* fill     = counts + n;               // n
  int* row_ptr  = fill + n;                 // n+4
  int* gs       = row_ptr + (n + 4);        // 68
  int* blocksum = gs + 68;                  // 1024
  float* dinv   = (float*)(blocksum + 1024);// n
  int* csr_src  = (int*)(dinv + n);         // E
  float* partial= (float*)(csr_src + E);    // 64*8*200
  _Float16* wt1 = (_Float16*)(partial + NG * POOL_NC * HIDW);  // 256*128
  _Float16* wt2 = wt1 + 256 * 128;
  _Float16* wt3 = wt2 + 256 * KPAD;
  _Float16* wtg = wt3 + 256 * KPAD;
  _Float16* xh   = wtg + 256 * KPAD;            // [n][128] f16 (dinv-scaled)
  _Float16* bufA = xh + (long)n * DIN;          // [n][224] f16
  _Float16* bufB = bufA + (long)n * KPAD;       // [n][224] f16

  hipMemsetAsync(counts, 0, (size_t)2 * n * sizeof(int), stream);  // counts + fill

  // weight prep: all 4 weights, one launch (256 padded cols, single f16 term)
  dim3 wgrid((256 * KPAD + 255) / 256, 4);
  wprep_kernel<<<wgrid, 256, 0, stream>>>(W1, W2, W3, Wg, wt1, wt2, wt3, wtg);

  int eb = (E + 255) / 256;
  build_kernel<<<eb, 256, 0, stream>>>(dst, counts, batch, gs, E, n);
  scan1_kernel<<<nb256, 256, 0, stream>>>(counts, blocksum, dinv, n);
  // cvt needs dinv (from scan1): g0 = dinv * x
  cvt_kernel<<<(n * 32 + 255) / 256, 256, 0, stream>>>(x, dinv, xh, n);
  scan2_kernel<<<1, 1024, 0, stream>>>(blocksum, nb256);
  scan3_kernel<<<nb256, 256, 0, stream>>>(counts, blocksum, row_ptr, n);
  fill_kernel<<<eb, 256, 0, stream>>>(src, dst, row_ptr, fill, csr_src, E);

  int ab = (n + 3) / 4;                          // agg blocks (wave per node)
  int gb = ((nb256 + 7) / 8) * 8 * 4;            // gemm: 8-aligned families x 4 strips

  // layer 1: z1 = agg(g0); bufB = dinv*relu(z1@W1+b1)
  agg_kernel<32><<<ab, 256, 0, stream>>>(xh, row_ptr, csr_src, dinv, bufA, n);
  mgemm_kernel<DIN, 1, 1><<<gb, 256, 0, stream>>>(bufA, wt1, b1, dinv, bufB, n);
  // layer 2
  agg_kernel<56><<<ab, 256, 0, stream>>>(bufB, row_ptr, csr_src, dinv, bufA, n);
  mgemm_kernel<KPAD, 1, 1><<<gb, 256, 0, stream>>>(bufA, wt2, b2, dinv, bufB, n);
  // layer 3 (h3 unscaled: feeds gate + pool, not another agg)
  agg_kernel<56><<<ab, 256, 0, stream>>>(bufB, row_ptr, csr_src, dinv, bufA, n);
  mgemm_kernel<KPAD, 1, 0><<<gb, 256, 0, stream>>>(bufA, wt3, b3, dinv, bufB, n);
  // gate + apply: bufA = h3 * sigmoid(h3 @ Wg + bg)
  mgemm_kernel<KPAD, 2, 0><<<gb, 256, 0, stream>>>(bufB, wtg, bg, dinv, bufA, n);
  // mean-pool partials + fused pool-final/classifier
  dim3 pgrid(NG, POOL_NC);
  pool_partial_kernel<<<pgrid, 256, 0, stream>>>(bufA, gs, partial, n);
  classifier_kernel<<<NG, 256, 0, stream>>>(partial, gs, Wc1, bc1, Wc2, bc2, out);
}

// Round 16
// 301.183 us; speedup vs baseline: 2.5558x; 1.0601x over previous
//
#include <hip/hip_runtime.h>

#define NG 64
#define HIDW 200
#define DIN 128
#define WKP 224          // weight k-dim (padded, zeros for k>=200)
#define POOL_NC 8

typedef _Float16 half4_t __attribute__((ext_vector_type(4)));
typedef _Float16 half8_t __attribute__((ext_vector_type(8)));
typedef float floatx4 __attribute__((ext_vector_type(4)));

// ---------------- build: degree count + graph-start table (fused) ----------------

__global__ void build_kernel(const int* __restrict__ dst, int* __restrict__ counts,
                             const int* __restrict__ batch, int* __restrict__ gs,
                             int E, int n) {
  int i = blockIdx.x * 256 + threadIdx.x;
  if (i < E) atomicAdd(&counts[dst[i]], 1);
  if (i < n) {
    int b = batch[i];
    if (i == 0) {
      for (int g = 0; g <= b; ++g) gs[g] = 0;
    } else {
      int bp = batch[i - 1];
      for (int g = bp + 1; g <= b; ++g) gs[g] = i;
    }
    if (i == n - 1) {
      for (int g = b + 1; g <= NG; ++g) gs[g] = n;
    }
  }
}

// ---------------- scan phase 1: per-block sums + dinv ----------------

__global__ __launch_bounds__(256) void scan1_kernel(const int* __restrict__ counts,
                                                    int* __restrict__ blocksum,
                                                    float* __restrict__ dinv, int n) {
  __shared__ int s[256];
  int tid = threadIdx.x;
  int i = blockIdx.x * 256 + tid;
  int c = (i < n) ? counts[i] : 0;
  if (i < n) dinv[i] = rsqrtf((float)(c + 1));
  s[tid] = c;
  __syncthreads();
#pragma unroll
  for (int off = 128; off > 0; off >>= 1) {
    if (tid < off) s[tid] += s[tid + off];
    __syncthreads();
  }
  if (tid == 0) blocksum[blockIdx.x] = s[0];
}

// ---------------- scan phase 2+3 fused: row_ptr (block offset computed in-block) ------

__global__ __launch_bounds__(256) void scan3_kernel(const int* __restrict__ counts,
                                                    const int* __restrict__ blocksum,
                                                    int* __restrict__ row_ptr, int n, int nb) {
  __shared__ int bs[256];
  __shared__ int s[256];
  int tid = threadIdx.x;
  // block offset = sum of blocksum[0..blockIdx.x)
  bs[tid] = (tid < blockIdx.x && tid < nb) ? blocksum[tid] : 0;
  __syncthreads();
#pragma unroll
  for (int off = 128; off > 0; off >>= 1) {
    if (tid < off) bs[tid] += bs[tid + off];
    __syncthreads();
  }
  int base = bs[0];

  int i = blockIdx.x * 256 + tid;
  int c = (i < n) ? counts[i] : 0;
  s[tid] = c;
  __syncthreads();
  for (int off = 1; off < 256; off <<= 1) {
    int t = (tid >= off) ? s[tid - off] : 0;
    __syncthreads();
    s[tid] += t;
    __syncthreads();
  }
  if (i < n) row_ptr[i] = base + s[tid] - c;
  if (i == n - 1) row_ptr[n] = base + s[tid];
}

__global__ void fill_kernel(const int* __restrict__ src, const int* __restrict__ dst,
                            const int* __restrict__ row_ptr, int* __restrict__ fill,
                            int* __restrict__ csr_src, int E) {
  int e = blockIdx.x * 256 + threadIdx.x;
  if (e >= E) return;
  int d = dst[e];
  int pos = row_ptr[d] + atomicAdd(&fill[d], 1);
  csr_src[pos] = src[e];
}

// ---------------- weight prep: W[k][200] fp32 -> WT [256][KP] f16, k>=200 zeroed ------

__global__ void wprep_kernel(const float* __restrict__ W1, const float* __restrict__ W2,
                             const float* __restrict__ W3, const float* __restrict__ Wg,
                             _Float16* __restrict__ o1, _Float16* __restrict__ o2,
                             _Float16* __restrict__ o3, _Float16* __restrict__ og) {
  int wsel = blockIdx.y;
  const float* W = (wsel == 0) ? W1 : (wsel == 1) ? W2 : (wsel == 2) ? W3 : Wg;
  _Float16* WT = (wsel == 0) ? o1 : (wsel == 1) ? o2 : (wsel == 2) ? o3 : og;
  int K  = (wsel == 0) ? DIN : HIDW;
  int KP = (wsel == 0) ? DIN : WKP;
  int idx = blockIdx.x * 256 + threadIdx.x;
  if (idx >= 256 * KP) return;
  int col = idx / KP, k = idx % KP;
  float v = (col < HIDW && k < K) ? W[(long)k * HIDW + col] : 0.f;
  WT[idx] = (_Float16)v;
}

// ---------------- x f32 [n][128] -> dinv-scaled row-major f16 [n][128] ----------------

__global__ void cvt_kernel(const float* __restrict__ x, const float* __restrict__ dinv,
                           _Float16* __restrict__ g0, int n) {
  int t = blockIdx.x * 256 + threadIdx.x;
  if (t >= n * 32) return;
  int node = t >> 5, q = t & 31;
  float di = dinv[node];
  float4 v = *(const float4*)&x[(long)node * 128 + q * 4];
  half4_t r = {(_Float16)(di * v.x), (_Float16)(di * v.y),
               (_Float16)(di * v.z), (_Float16)(di * v.w)};
  ((half4_t*)g0)[(long)node * 32 + q] = r;
}

// ---------------- aggregation: z[i] = dinv[i] * (g[i] + sum_{s in N(i)} g[s]) ---------
// g pre-scaled by dinv. Row-major [n][C*4] f16 (C=32: 128 feats; C=50: 200 feats,
// no pad bytes -> 12% less fetch). Wave per node; unroll 16, tails 8/4/1.

template <int C>
__global__ __launch_bounds__(256) void agg_kernel(const _Float16* __restrict__ g,
                                                  const int* __restrict__ row_ptr,
                                                  const int* __restrict__ csr_src,
                                                  const float* __restrict__ dinv,
                                                  _Float16* __restrict__ out, int n) {
  int node = blockIdx.x * 4 + (threadIdx.x >> 6);
  int lane = threadIdx.x & 63;
  if (node >= n || lane >= C) return;
  const half4_t* __restrict__ hp = (const half4_t*)g;
  int e0 = row_ptr[node], e1 = row_ptr[node + 1];
  half4_t self = hp[(long)node * C + lane];
  float ax = (float)self.x, ay = (float)self.y;
  float az = (float)self.z, aw = (float)self.w;

  int e = e0;
  for (; e + 16 <= e1; e += 16) {
    int sI[16];
#pragma unroll
    for (int j = 0; j < 16; ++j) sI[j] = csr_src[e + j];
    half4_t vv[16];
#pragma unroll
    for (int j = 0; j < 16; ++j) vv[j] = hp[(long)sI[j] * C + lane];
#pragma unroll
    for (int j = 0; j < 16; ++j) {
      ax += (float)vv[j].x; ay += (float)vv[j].y;
      az += (float)vv[j].z; aw += (float)vv[j].w;
    }
  }
  if (e + 8 <= e1) {
    int sI[8];
#pragma unroll
    for (int j = 0; j < 8; ++j) sI[j] = csr_src[e + j];
    half4_t vv[8];
#pragma unroll
    for (int j = 0; j < 8; ++j) vv[j] = hp[(long)sI[j] * C + lane];
#pragma unroll
    for (int j = 0; j < 8; ++j) {
      ax += (float)vv[j].x; ay += (float)vv[j].y;
      az += (float)vv[j].z; aw += (float)vv[j].w;
    }
    e += 8;
  }
  if (e + 4 <= e1) {
    int sI[4];
#pragma unroll
    for (int j = 0; j < 4; ++j) sI[j] = csr_src[e + j];
    half4_t vv[4];
#pragma unroll
    for (int j = 0; j < 4; ++j) vv[j] = hp[(long)sI[j] * C + lane];
#pragma unroll
    for (int j = 0; j < 4; ++j) {
      ax += (float)vv[j].x; ay += (float)vv[j].y;
      az += (float)vv[j].z; aw += (float)vv[j].w;
    }
    e += 4;
  }
  for (; e < e1; ++e) {
    int s = csr_src[e];
    half4_t v = hp[(long)s * C + lane];
    ax += (float)v.x; ay += (float)v.y; az += (float)v.z; aw += (float)v.w;
  }
  float di = dinv[node];
  half4_t r = {(_Float16)(di * ax), (_Float16)(di * ay),
               (_Float16)(di * az), (_Float16)(di * aw)};
  ((half4_t*)out)[(long)node * C + lane] = r;
}

// ---------------- MFMA GEMM: LDS B-panel + XCD-family swizzle, 32-row waves -----------
// A: [N][AS] f16 (AS=200: k-steps overhang into next row x W-pad ZEROS = exact).
// W: [256][KP] f16 (k>=200 zero). out: [N][200] f16.
// Block = 4 waves x 32-row tiles (128 rows) x one 64-col strip -> 1280 blocks
// (~4.9 waves/SIMD vs R15's 2.45 — grid-bound occupancy fix, R10 lesson).
// Swizzle: strip=(b>>3)&3, rg=(b&7)+8*(b>>5); strips of a row-group share b%8 -> XCD.
// MODE 1 = relu, 2 = gated. DSCALE: out *= dinv[row].

template <int KP, int AS, int MODE, int DSCALE>
__global__ __launch_bounds__(256, 4) void mgemm_kernel(const _Float16* __restrict__ A,
                                                       const _Float16* __restrict__ WT,
                                                       const float* __restrict__ bias,
                                                       const float* __restrict__ dinv,
                                                       _Float16* __restrict__ out, int N) {
  constexpr int LDK = KP + 8;
  __shared__ _Float16 Bs[64][LDK];
  int tid = threadIdx.x;
  int b = blockIdx.x;
  int strip = (b >> 3) & 3;
  int rg = (b & 7) + 8 * (b >> 5);
  int col0 = strip * 64;

  // stage B: 64 cols x KP, once
  {
    int c = tid >> 2;
    int ks = (tid & 3) * (KP / 4);
    const _Float16* gw = WT + (long)(col0 + c) * KP + ks;
#pragma unroll
    for (int j = 0; j < KP / 32; ++j)
      *(half8_t*)&Bs[c][ks + j * 8] = *(const half8_t*)(gw + j * 8);
  }
  __syncthreads();

  int lane = tid & 63;
  int wid = tid >> 6;
  int row0 = rg * 128 + wid * 32;
  if (row0 >= N) return;  // no barriers after this point
  int l15 = lane & 15;
  int lq = lane >> 4;

  const _Float16* __restrict__ pa = A + (long)(row0 + l15) * AS + lq * 8;

  floatx4 acc[2][4];
#pragma unroll
  for (int i = 0; i < 2; ++i)
#pragma unroll
    for (int j = 0; j < 4; ++j) acc[i][j] = (floatx4){0.f, 0.f, 0.f, 0.f};

#pragma unroll
  for (int k0 = 0; k0 < KP; k0 += 32) {
    half8_t a[2];
#pragma unroll
    for (int rf = 0; rf < 2; ++rf)
      a[rf] = *(const half8_t*)(pa + (long)rf * 16 * AS + k0);
#pragma unroll
    for (int cf = 0; cf < 4; ++cf) {
      half8_t bv = *(const half8_t*)&Bs[cf * 16 + l15][k0 + lq * 8];
#pragma unroll
      for (int rf = 0; rf < 2; ++rf)
        acc[rf][cf] = __builtin_amdgcn_mfma_f32_16x16x32_f16(a[rf], bv, acc[rf][cf], 0, 0, 0);
    }
  }

#pragma unroll
  for (int cf = 0; cf < 4; ++cf) {
    int col = col0 + cf * 16 + l15;
    if (col >= HIDW) continue;      // cols 200..255 not stored (no pads in layout)
    float bs = bias[col];
#pragma unroll
    for (int rf = 0; rf < 2; ++rf) {
      int rbase = row0 + rf * 16 + lq * 4;
#pragma unroll
      for (int j = 0; j < 4; ++j) {
        int row = rbase + j;
        float v = acc[rf][cf][j] + bs;
        if (MODE == 1) v = fmaxf(v, 0.f);
        if (MODE == 2) {
          float hv = (float)A[(long)row * AS + col];
          v = hv * (1.f / (1.f + __expf(-v)));
        }
        if (DSCALE) v *= dinv[row];
        out[(long)row * HIDW + col] = (_Float16)v;
      }
    }
  }
}

// ---------------- mean pool partials over gated row-major f16 [n][200] ----------------

__global__ __launch_bounds__(256) void pool_partial_kernel(const _Float16* __restrict__ gated,
                                                           const int* __restrict__ gs,
                                                           float* __restrict__ partial, int n) {
  int g = blockIdx.x;
  int c = blockIdx.y;
  int f = threadIdx.x;
  int s = gs[g], e = gs[g + 1];
  int len = e - s;
  int chunk = (len + POOL_NC - 1) / POOL_NC;
  int i0 = s + c * chunk;
  int i1 = i0 + chunk; if (i1 > e) i1 = e;
  if (f < HIDW) {
    float acc = 0.f;
    for (int i = i0; i < i1; ++i) acc += (float)gated[(long)i * HIDW + f];
    partial[(g * POOL_NC + c) * HIDW + f] = acc;
  }
}

// ---------------- classifier (fused pool-final): partial -> logits ----------------

__global__ void classifier_kernel(const float* __restrict__ partial,
                                  const int* __restrict__ gs,
                                  const float* __restrict__ Wc1, const float* __restrict__ bc1,
                                  const float* __restrict__ Wc2, const float* __restrict__ bc2,
                                  float* __restrict__ out) {
  int g = blockIdx.x;
  int tid = threadIdx.x;
  __shared__ float pg[HIDW];
  __shared__ float hid[100];
  if (tid < HIDW) {
    float acc = 0.f;
#pragma unroll
    for (int c = 0; c < POOL_NC; ++c) acc += partial[(g * POOL_NC + c) * HIDW + tid];
    float cnt = fmaxf((float)(gs[g + 1] - gs[g]), 1.f);
    pg[tid] = acc / cnt;
  }
  __syncthreads();
  if (tid < 100) {
    float a = bc1[tid];
    for (int k = 0; k < HIDW; ++k) a = fmaf(pg[k], Wc1[k * 100 + tid], a);
    hid[tid] = fmaxf(a, 0.f);
  }
  __syncthreads();
  if (tid < 2) {
    float a = bc2[tid];
    for (int k = 0; k < 100; ++k) a = fmaf(hid[k], Wc2[k * 2 + tid], a);
    out[g * 2 + tid] = a;
  }
}

// ---------------- launch ----------------

extern "C" void kernel_launch(void* const* d_in, const int* in_sizes, int n_in,
                              void* d_out, int out_size, void* d_ws, size_t ws_size,
                              hipStream_t stream) {
  const float* x    = (const float*)d_in[0];
  const int*   ei   = (const int*)d_in[1];
  const int*   batch= (const int*)d_in[2];
  const float* W1 = (const float*)d_in[3];  const float* b1 = (const float*)d_in[4];
  const float* W2 = (const float*)d_in[5];  const float* b2 = (const float*)d_in[6];
  const float* W3 = (const float*)d_in[7];  const float* b3 = (const float*)d_in[8];
  const float* Wg = (const float*)d_in[9];  const float* bg = (const float*)d_in[10];
  const float* Wc1= (const float*)d_in[11]; const float* bc1= (const float*)d_in[12];
  const float* Wc2= (const float*)d_in[13]; const float* bc2= (const float*)d_in[14];
  float* out = (float*)d_out;

  const int n = in_sizes[0] / DIN;     // 40000
  const int E = in_sizes[1] / 2;       // 640000
  const int* src = ei;
  const int* dst = ei + E;
  const int nb256 = (n + 255) / 256;   // 157 scan blocks

  // workspace carve-up (all segments 16B-aligned)
  int* counts   = (int*)d_ws;               // n
  int* fill     = counts + n;               // n
  int* row_ptr  = fill + n;                 // n+4
  int* gs       = row_ptr + (n + 4);        // 68
  int* blocksum = gs + 68;                  // 1024
  float* dinv   = (float*)(blocksum + 1024);// n
  int* csr_src  = (int*)(dinv + n);         // E
  float* partial= (float*)(csr_src + E);    // 64*8*200
  _Float16* wt1 = (_Float16*)(partial + NG * POOL_NC * HIDW);  // 256*128
  _Float16* wt2 = wt1 + 256 * DIN;
  _Float16* wt3 = wt2 + 256 * WKP;
  _Float16* wtg = wt3 + 256 * WKP;
  _Float16* xh   = wtg + 256 * WKP;             // [n][128] f16 (dinv-scaled)
  _Float16* bufA = xh + (long)n * DIN;          // [n][200] f16 (+64 tail)
  _Float16* bufB = bufA + (long)n * HIDW + 64;  // [n][200] f16 (+64 tail)

  hipMemsetAsync(counts, 0, (size_t)2 * n * sizeof(int), stream);  // counts + fill

  // weight prep: all 4 weights, one launch
  dim3 wgrid((256 * WKP + 255) / 256, 4);
  wprep_kernel<<<wgrid, 256, 0, stream>>>(W1, W2, W3, Wg, wt1, wt2, wt3, wtg);

  int eb = (E + 255) / 256;
  build_kernel<<<eb, 256, 0, stream>>>(dst, counts, batch, gs, E, n);
  scan1_kernel<<<nb256, 256, 0, stream>>>(counts, blocksum, dinv, n);
  // cvt needs dinv (from scan1): g0 = dinv * x
  cvt_kernel<<<(n * 32 + 255) / 256, 256, 0, stream>>>(x, dinv, xh, n);
  scan3_kernel<<<nb256, 256, 0, stream>>>(counts, blocksum, row_ptr, n, nb256);
  fill_kernel<<<eb, 256, 0, stream>>>(src, dst, row_ptr, fill, csr_src, E);

  int ab = (n + 3) / 4;                          // agg blocks (wave per node)
  int nrg = (n + 127) / 128;                     // 313 row-groups (128 rows each)
  int gb = ((nrg + 7) / 8) * 8 * 4;              // 1280: 8-aligned families x 4 strips

  // layer 1: z1 = agg(g0); bufB = dinv*relu(z1@W1+b1)
  agg_kernel<32><<<ab, 256, 0, stream>>>(xh, row_ptr, csr_src, dinv, bufA, n);
  mgemm_kernel<DIN, DIN, 1, 1><<<gb, 256, 0, stream>>>(bufA, wt1, b1, dinv, bufB, n);
  // layer 2
  agg_kernel<50><<<ab, 256, 0, stream>>>(bufB, row_ptr, csr_src, dinv, bufA, n);
  mgemm_kernel<WKP, HIDW, 1, 1><<<gb, 256, 0, stream>>>(bufA, wt2, b2, dinv, bufB, n);
  // layer 3 (h3 unscaled: feeds gate + pool, not another agg)
  agg_kernel<50><<<ab, 256, 0, stream>>>(bufB, row_ptr, csr_src, dinv, bufA, n);
  mgemm_kernel<WKP, HIDW, 1, 0><<<gb, 256, 0, stream>>>(bufA, wt3, b3, dinv, bufB, n);
  // gate + apply: bufA = h3 * sigmoid(h3 @ Wg + bg)
  mgemm_kernel<WKP, HIDW, 2, 0><<<gb, 256, 0, stream>>>(bufB, wtg, bg, dinv, bufA, n);
  // mean-pool partials + fused pool-final/classifier
  dim3 pgrid(NG, POOL_NC);
  pool_partial_kernel<<<pgrid, 256, 0, stream>>>(bufA, gs, partial, n);
  classifier_kernel<<<NG, 256, 0, stream>>>(partial, gs, Wc1, bc1, Wc2, bc2, out);
}